// Round 1
// baseline (1426.870 us; speedup 1.0000x reference)
//
#include <hip/hip_runtime.h>

#define F_IN 128
#define F_OUT 64

// ---------------- degree (dst occurrences; +1 self-loop added later) --------
__global__ __launch_bounds__(256) void deg_kernel(const int* __restrict__ ei,
                                                  int* __restrict__ deg,
                                                  int N, int E) {
    int r = blockIdx.y;
    int e = blockIdx.x * 256 + threadIdx.x;
    if (e >= E) return;
    int d = ei[(size_t)r * 2 * E + E + e];
    atomicAdd(&deg[(size_t)r * N + d], 1);
}

__global__ __launch_bounds__(256) void dinv_kernel(const int* __restrict__ deg,
                                                   float* __restrict__ dinv,
                                                   int total) {
    int i = blockIdx.x * 256 + threadIdx.x;
    if (i >= total) return;
    dinv[i] = rsqrtf((float)(deg[i] + 1));   // self-loop => deg >= 1 always
}

// ---------------- XW = x @ W_r  (N x 128 @ 128 x 64) ------------------------
// Wave = one 8-row group; lane = output column. W_r staged in LDS (32 KB).
// 8 rows per thread amortizes each ds_read across 8 FMAs.
__global__ __launch_bounds__(256) void gemm_xw(const float* __restrict__ x,
                                               const float* __restrict__ W,
                                               float* __restrict__ xw,
                                               int N) {
    __shared__ float sW[F_IN * F_OUT];
    int r = blockIdx.y;
    const float* Wr = W + (size_t)r * F_IN * F_OUT;
    for (int i = threadIdx.x; i < F_IN * F_OUT; i += 256) sW[i] = Wr[i];
    __syncthreads();

    int col = threadIdx.x & 63;
    int wv  = threadIdx.x >> 6;
    int row0 = (blockIdx.x * 4 + wv) * 8;
    if (row0 >= N) return;

    int nr = N - row0; if (nr > 8) nr = 8;
    if (nr == 8) {
        float acc[8] = {0.f,0.f,0.f,0.f,0.f,0.f,0.f,0.f};
        for (int k4 = 0; k4 < F_IN / 4; ++k4) {
            float4 xv[8];
            #pragma unroll
            for (int j = 0; j < 8; ++j)
                xv[j] = *(const float4*)(x + (size_t)(row0 + j) * F_IN + k4 * 4);
            #pragma unroll
            for (int kk = 0; kk < 4; ++kk) {
                float w = sW[(k4 * 4 + kk) * F_OUT + col];
                #pragma unroll
                for (int j = 0; j < 8; ++j) {
                    float xs = (kk == 0) ? xv[j].x : (kk == 1) ? xv[j].y
                             : (kk == 2) ? xv[j].z : xv[j].w;
                    acc[j] += xs * w;
                }
            }
        }
        #pragma unroll
        for (int j = 0; j < 8; ++j)
            xw[((size_t)r * N + row0 + j) * F_OUT + col] = acc[j];
    } else {
        for (int j = 0; j < nr; ++j) {
            float a = 0.f;
            for (int k = 0; k < F_IN; ++k)
                a += x[(size_t)(row0 + j) * F_IN + k] * sW[k * F_OUT + col];
            xw[((size_t)r * N + row0 + j) * F_OUT + col] = a;
        }
    }
}

// ---------------- self-loop term initializes the accumulators ---------------
// Each (r,i) row written exactly once -> plain stores, replaces zero-init.
__global__ __launch_bounds__(256) void selfloop_init(const float* __restrict__ xw,
                                                     const float* __restrict__ dinv,
                                                     const int* __restrict__ perm,
                                                     float* __restrict__ out_pos,
                                                     float* __restrict__ out_neg,
                                                     int N) {
    int r = blockIdx.y;
    int lane = threadIdx.x & 63;
    int i = blockIdx.x * 4 + (threadIdx.x >> 6);
    if (i >= N) return;
    float dv = dinv[(size_t)r * N + i];
    float w = dv * dv;
    size_t base = (size_t)r * N * F_OUT;
    out_pos[base + (size_t)i * F_OUT + lane] =
        xw[base + (size_t)i * F_OUT + lane] * w;
    int pi = perm[(size_t)r * N + i];
    out_neg[base + (size_t)i * F_OUT + lane] =
        xw[base + (size_t)pi * F_OUT + lane] * w;
}

// ---------------- edge scatter: one wave per edge, lane = column ------------
__global__ __launch_bounds__(256) void scatter_edges(const int* __restrict__ ei,
                                                     const int* __restrict__ perm,
                                                     const float* __restrict__ dinv,
                                                     const float* __restrict__ xw,
                                                     float* __restrict__ out_pos,
                                                     float* __restrict__ out_neg,
                                                     int N, int E) {
    int r = blockIdx.y;
    int lane = threadIdx.x & 63;
    int e = blockIdx.x * 4 + (threadIdx.x >> 6);
    if (e >= E) return;
    const int* src = ei + (size_t)r * 2 * E;
    int s = src[e];
    int d = src[E + e];
    const float* dv = dinv + (size_t)r * N;
    float nrm = dv[s] * dv[d];
    size_t base = (size_t)r * N * F_OUT;
    float vp = xw[base + (size_t)s * F_OUT + lane] * nrm;
    atomicAdd(&out_pos[base + (size_t)d * F_OUT + lane], vp);
    int ps = perm[(size_t)r * N + s];
    float vn = xw[base + (size_t)ps * F_OUT + lane] * nrm;
    atomicAdd(&out_neg[base + (size_t)d * F_OUT + lane], vn);
}

// ---------------- bias + relu in-place, summary = mean of pos ---------------
__global__ __launch_bounds__(256) void epilogue(float* __restrict__ out_pos,
                                                float* __restrict__ out_neg,
                                                const float* __restrict__ bs,
                                                float* __restrict__ summary,
                                                int N, float inv_n) {
    int r = blockIdx.y;
    int lane = threadIdx.x & 63;
    int wv = threadIdx.x >> 6;
    float b = bs[r * F_OUT + lane];
    float sum = 0.f;
    size_t base = (size_t)r * N * F_OUT;
    for (int i = blockIdx.x * 4 + wv; i < N; i += gridDim.x * 4) {
        size_t off = base + (size_t)i * F_OUT + lane;
        float p = out_pos[off] + b;
        p = p > 0.f ? p : 0.f;
        out_pos[off] = p;
        sum += p;
        float q = out_neg[off] + b;
        out_neg[off] = q > 0.f ? q : 0.f;
    }
    __shared__ float ls[4 * 64];
    ls[wv * 64 + lane] = sum;
    __syncthreads();
    if (wv == 0) {
        float t = ls[lane] + ls[64 + lane] + ls[128 + lane] + ls[192 + lane];
        atomicAdd(&summary[r * F_OUT + lane], t * inv_n);
    }
}

extern "C" void kernel_launch(void* const* d_in, const int* in_sizes, int n_in,
                              void* d_out, int out_size, void* d_ws, size_t ws_size,
                              hipStream_t stream) {
    const float* x    = (const float*)d_in[0];
    const int*   ei   = (const int*)d_in[1];
    const int*   perm = (const int*)d_in[2];
    const float* Ws   = (const float*)d_in[3];
    const float* bs   = (const float*)d_in[4];

    const int N = in_sizes[0] / F_IN;          // 100000
    const int R = in_sizes[4] / F_OUT;         // 3
    const int E = in_sizes[1] / (2 * R);       // 600000

    float* out_pos = (float*)d_out;
    float* out_neg = out_pos + (size_t)R * N * F_OUT;
    float* summary = out_neg + (size_t)R * N * F_OUT;

    char* ws = (char*)d_ws;
    int*   deg  = (int*)ws;                                   // R*N ints
    float* dinv = (float*)(ws + (size_t)R * N * 4);           // R*N floats
    float* xw   = (float*)(ws + (size_t)R * N * 8);           // R*N*64 floats

    hipMemsetAsync(deg, 0, (size_t)R * N * sizeof(int), stream);
    hipMemsetAsync(summary, 0, (size_t)R * F_OUT * sizeof(float), stream);

    deg_kernel<<<dim3((E + 255) / 256, R), 256, 0, stream>>>(ei, deg, N, E);
    dinv_kernel<<<(R * N + 255) / 256, 256, 0, stream>>>(deg, dinv, R * N);
    gemm_xw<<<dim3((N + 31) / 32, R), 256, 0, stream>>>(x, Ws, xw, N);
    selfloop_init<<<dim3((N + 3) / 4, R), 256, 0, stream>>>(xw, dinv, perm,
                                                            out_pos, out_neg, N);
    scatter_edges<<<dim3((E + 3) / 4, R), 256, 0, stream>>>(ei, perm, dinv, xw,
                                                            out_pos, out_neg, N, E);
    epilogue<<<dim3(512, R), 256, 0, stream>>>(out_pos, out_neg, bs, summary,
                                               N, 1.0f / (float)N);
}

// Round 2
// 1089.564 us; speedup vs baseline: 1.3096x; 1.3096x over previous
//
#include <hip/hip_runtime.h>

#define F_IN 128
#define F_OUT 64

// ---------------- degree (dst occurrences; +1 self-loop added later) --------
__global__ __launch_bounds__(256) void deg_kernel(const int* __restrict__ ei,
                                                  int* __restrict__ deg,
                                                  int N, int E) {
    int r = blockIdx.y;
    int e = blockIdx.x * 256 + threadIdx.x;
    if (e >= E) return;
    int d = ei[(size_t)r * 2 * E + E + e];
    atomicAdd(&deg[(size_t)r * N + d], 1);
}

// ---------------- exclusive scan per relation; also dinv = rsqrt(deg+1) -----
// One block per relation, 1024 elems/iter (4/thread). deg buffer is rewritten
// in-place with the exclusive prefix (becomes the fill cursor).
__global__ __launch_bounds__(256) void scan_kernel(int* __restrict__ deg,
                                                   int* __restrict__ rowstart,
                                                   float* __restrict__ dinv,
                                                   int N) {
    int r = blockIdx.x;
    int tid = threadIdx.x;
    int lane = tid & 63, wv = tid >> 6;
    __shared__ int wsum[4];
    int* dg = deg + (size_t)r * N;
    int* rs = rowstart + (size_t)r * (N + 1);
    float* dv = dinv + (size_t)r * N;
    int carry = 0;
    for (int base = 0; base < N; base += 1024) {
        int v[4]; int tsum = 0;
        #pragma unroll
        for (int j = 0; j < 4; ++j) {
            int idx = base + tid * 4 + j;
            v[j] = (idx < N) ? dg[idx] : 0;
            tsum += v[j];
        }
        int sc = tsum;
        #pragma unroll
        for (int off = 1; off < 64; off <<= 1) {
            int t = __shfl_up(sc, off, 64);
            if (lane >= off) sc += t;
        }
        if (lane == 63) wsum[wv] = sc;
        __syncthreads();
        int woff = 0;
        for (int w = 0; w < wv; ++w) woff += wsum[w];
        int excl = carry + woff + sc - tsum;
        #pragma unroll
        for (int j = 0; j < 4; ++j) {
            int idx = base + tid * 4 + j;
            if (idx < N) {
                rs[idx] = excl;
                dg[idx] = excl;                       // cursor for fill_csr
                dv[idx] = rsqrtf((float)(v[j] + 1));  // +1 self-loop
            }
            excl += v[j];
        }
        int total = wsum[0] + wsum[1] + wsum[2] + wsum[3];
        __syncthreads();
        carry += total;
    }
    if (tid == 0) rs[N] = carry;
}

// ---------------- fill CSR: bucket edges by dst; store (src, perm[src]) -----
__global__ __launch_bounds__(256) void fill_csr(const int* __restrict__ ei,
                                                const int* __restrict__ perm,
                                                int* __restrict__ cursor,
                                                int2* __restrict__ csr,
                                                int N, int E) {
    int r = blockIdx.y;
    int e = blockIdx.x * 256 + threadIdx.x;
    if (e >= E) return;
    const int* base = ei + (size_t)r * 2 * E;
    int s = base[e], d = base[E + e];
    int pos = atomicAdd(&cursor[(size_t)r * N + d], 1);
    int2 sp; sp.x = s; sp.y = perm[(size_t)r * N + s];
    csr[(size_t)r * E + pos] = sp;
}

// ---------------- XW = x @ W_r  (N x 128 @ 128 x 64) ------------------------
__global__ __launch_bounds__(256) void gemm_xw(const float* __restrict__ x,
                                               const float* __restrict__ W,
                                               float* __restrict__ xw,
                                               int N) {
    __shared__ float sW[F_IN * F_OUT];
    int r = blockIdx.y;
    const float* Wr = W + (size_t)r * F_IN * F_OUT;
    for (int i = threadIdx.x; i < F_IN * F_OUT; i += 256) sW[i] = Wr[i];
    __syncthreads();

    int col = threadIdx.x & 63;
    int wv  = threadIdx.x >> 6;
    int row0 = (blockIdx.x * 4 + wv) * 8;
    if (row0 >= N) return;

    int nr = N - row0; if (nr > 8) nr = 8;
    if (nr == 8) {
        float acc[8] = {0.f,0.f,0.f,0.f,0.f,0.f,0.f,0.f};
        for (int k4 = 0; k4 < F_IN / 4; ++k4) {
            float4 xv[8];
            #pragma unroll
            for (int j = 0; j < 8; ++j)
                xv[j] = *(const float4*)(x + (size_t)(row0 + j) * F_IN + k4 * 4);
            #pragma unroll
            for (int kk = 0; kk < 4; ++kk) {
                float w = sW[(k4 * 4 + kk) * F_OUT + col];
                #pragma unroll
                for (int j = 0; j < 8; ++j) {
                    float xs = (kk == 0) ? xv[j].x : (kk == 1) ? xv[j].y
                             : (kk == 2) ? xv[j].z : xv[j].w;
                    acc[j] += xs * w;
                }
            }
        }
        #pragma unroll
        for (int j = 0; j < 8; ++j)
            xw[((size_t)r * N + row0 + j) * F_OUT + col] = acc[j];
    } else {
        for (int j = 0; j < nr; ++j) {
            float a = 0.f;
            for (int k = 0; k < F_IN; ++k)
                a += x[(size_t)(row0 + j) * F_IN + k] * sW[k * F_OUT + col];
            xw[((size_t)r * N + row0 + j) * F_OUT + col] = a;
        }
    }
}

// ---------------- gather: one wave per (r, dst row); fused epilogue ---------
__global__ __launch_bounds__(256) void gather_kernel(const int2* __restrict__ csr,
                                                     const int* __restrict__ rowstart,
                                                     const float* __restrict__ dinv,
                                                     const int* __restrict__ perm,
                                                     const float* __restrict__ xw,
                                                     const float* __restrict__ bs,
                                                     float* __restrict__ out_pos,
                                                     float* __restrict__ out_neg,
                                                     float* __restrict__ partial,
                                                     int N, int E) {
    int r = blockIdx.y;
    int lane = threadIdx.x & 63, wv = threadIdx.x >> 6;
    int i = blockIdx.x * 4 + wv;
    __shared__ float ls[256];
    float psum = 0.f;
    if (i < N) {
        const float* dv  = dinv + (size_t)r * N;
        const float* xwr = xw + (size_t)r * N * F_OUT;
        float di = dv[i];
        float w = di * di;
        float accp = xwr[(size_t)i * F_OUT + lane] * w;
        int pi = perm[(size_t)r * N + i];
        float accn = xwr[(size_t)pi * F_OUT + lane] * w;
        const int* rs = rowstart + (size_t)r * (N + 1);
        int j0 = rs[i], j1 = rs[i + 1];
        const int2* cs = csr + (size_t)r * E;
        for (int j = j0; j < j1; ++j) {
            int2 sp = cs[j];
            float nrm = dv[sp.x] * di;
            accp += xwr[(size_t)sp.x * F_OUT + lane] * nrm;
            accn += xwr[(size_t)sp.y * F_OUT + lane] * nrm;
        }
        float b = bs[r * F_OUT + lane];
        float p = accp + b; p = p > 0.f ? p : 0.f;
        float q = accn + b; q = q > 0.f ? q : 0.f;
        size_t off = (size_t)r * N * F_OUT + (size_t)i * F_OUT + lane;
        out_pos[off] = p;
        out_neg[off] = q;
        psum = p;
    }
    ls[threadIdx.x] = psum;
    __syncthreads();
    if (wv == 0) {
        float t = ls[lane] + ls[64 + lane] + ls[128 + lane] + ls[192 + lane];
        // ~98 blocks share each slot -> negligible contention
        atomicAdd(&partial[((size_t)r * 256 + (blockIdx.x & 255)) * F_OUT + lane], t);
    }
}

// ---------------- summary = mean over pos rows ------------------------------
__global__ __launch_bounds__(256) void summary_reduce(const float* __restrict__ partial,
                                                      float* __restrict__ summary,
                                                      float inv_n) {
    int r = blockIdx.x;
    int lane = threadIdx.x & 63, wv = threadIdx.x >> 6;
    __shared__ float ls[256];
    float s = 0.f;
    for (int c = wv; c < 256; c += 4)
        s += partial[((size_t)r * 256 + c) * F_OUT + lane];
    ls[threadIdx.x] = s;
    __syncthreads();
    if (wv == 0)
        summary[r * F_OUT + lane] =
            (ls[lane] + ls[64 + lane] + ls[128 + lane] + ls[192 + lane]) * inv_n;
}

extern "C" void kernel_launch(void* const* d_in, const int* in_sizes, int n_in,
                              void* d_out, int out_size, void* d_ws, size_t ws_size,
                              hipStream_t stream) {
    const float* x    = (const float*)d_in[0];
    const int*   ei   = (const int*)d_in[1];
    const int*   perm = (const int*)d_in[2];
    const float* Ws   = (const float*)d_in[3];
    const float* bs   = (const float*)d_in[4];

    const int N = in_sizes[0] / F_IN;          // 100000
    const int R = in_sizes[4] / F_OUT;         // 3
    const int E = in_sizes[1] / (2 * R);       // 600000

    float* out_pos = (float*)d_out;
    float* out_neg = out_pos + (size_t)R * N * F_OUT;
    float* summary = out_neg + (size_t)R * N * F_OUT;

    // ---- workspace layout (16B-aligned chunks) ----
    char* ws = (char*)d_ws;
    size_t off = 0;
    auto alloc = [&](size_t bytes) { void* p = ws + off;
        off += (bytes + 15) & ~(size_t)15; return p; };
    int*   deg      = (int*)  alloc((size_t)R * N * 4);        // -> cursor after scan
    float* dinv     = (float*)alloc((size_t)R * N * 4);
    int*   rowstart = (int*)  alloc((size_t)R * (N + 1) * 4);
    int2*  csr      = (int2*) alloc((size_t)R * E * 8);
    float* xw       = (float*)alloc((size_t)R * N * F_OUT * 4);
    float* partial  = (float*)alloc((size_t)R * 256 * F_OUT * 4);

    hipMemsetAsync(deg, 0, (size_t)R * N * sizeof(int), stream);
    hipMemsetAsync(partial, 0, (size_t)R * 256 * F_OUT * sizeof(float), stream);

    deg_kernel<<<dim3((E + 255) / 256, R), 256, 0, stream>>>(ei, deg, N, E);
    scan_kernel<<<R, 256, 0, stream>>>(deg, rowstart, dinv, N);
    fill_csr<<<dim3((E + 255) / 256, R), 256, 0, stream>>>(ei, perm, deg, csr, N, E);
    gemm_xw<<<dim3((N + 31) / 32, R), 256, 0, stream>>>(x, Ws, xw, N);
    gather_kernel<<<dim3((N + 3) / 4, R), 256, 0, stream>>>(csr, rowstart, dinv, perm,
                                                            xw, bs, out_pos, out_neg,
                                                            partial, N, E);
    summary_reduce<<<R, 256, 0, stream>>>(partial, summary, 1.0f / (float)N);
}

// Round 3
// 659.729 us; speedup vs baseline: 2.1628x; 1.6515x over previous
//
#include <hip/hip_runtime.h>

#define F_IN 128
#define F_OUT 64
#define NCHUNK 256   // scan chunks per relation

// ---------------- degree (dst occurrences; +1 self-loop added later) --------
__global__ __launch_bounds__(256) void deg_kernel(const int* __restrict__ ei,
                                                  int* __restrict__ deg,
                                                  int N, int E) {
    int r = blockIdx.y;
    int e = blockIdx.x * 256 + threadIdx.x;
    if (e >= E) return;
    int d = ei[(size_t)r * 2 * E + E + e];
    atomicAdd(&deg[(size_t)r * N + d], 1);
}

// ---------------- hierarchical scan, phase 1: per-chunk sums ----------------
__global__ __launch_bounds__(256) void scan_partial(const int* __restrict__ deg,
                                                    int* __restrict__ psum,
                                                    int N, int chunk) {
    int r = blockIdx.y, b = blockIdx.x;
    int start = b * chunk, end = min(start + chunk, N);
    int s = 0;
    for (int i = start + threadIdx.x; i < end; i += 256)
        s += deg[(size_t)r * N + i];
    __shared__ int ls[256];
    ls[threadIdx.x] = s;
    __syncthreads();
    for (int off = 128; off > 0; off >>= 1) {
        if (threadIdx.x < off) ls[threadIdx.x] += ls[threadIdx.x + off];
        __syncthreads();
    }
    if (threadIdx.x == 0) psum[r * NCHUNK + b] = ls[0];
}

// ---------------- phase 2: exclusive scan of chunk sums (1 block) -----------
__global__ __launch_bounds__(256) void scan_offsets(int* __restrict__ psum,
                                                    int* __restrict__ rowstart,
                                                    int N, int R) {
    int tid = threadIdx.x, lane = tid & 63, wv = tid >> 6;
    __shared__ int wsum[4];
    for (int r = 0; r < R; ++r) {
        int v = psum[r * NCHUNK + tid];
        int sc = v;
        #pragma unroll
        for (int off = 1; off < 64; off <<= 1) {
            int t = __shfl_up(sc, off, 64);
            if (lane >= off) sc += t;
        }
        if (lane == 63) wsum[wv] = sc;
        __syncthreads();
        int woff = 0;
        for (int w = 0; w < wv; ++w) woff += wsum[w];
        psum[r * NCHUNK + tid] = woff + sc - v;   // exclusive
        if (tid == 255) rowstart[(size_t)r * (N + 1) + N] = woff + sc;  // total
        __syncthreads();
    }
}

// ---------------- phase 3: re-scan chunk, write rowstart/cursor/dinv --------
__global__ __launch_bounds__(256) void scan_apply(int* __restrict__ deg,
                                                  const int* __restrict__ psum,
                                                  int* __restrict__ rowstart,
                                                  float* __restrict__ dinv,
                                                  int N, int chunk) {
    int r = blockIdx.y, b = blockIdx.x;
    int tid = threadIdx.x, lane = tid & 63, wv = tid >> 6;
    int start = b * chunk, end = min(start + chunk, N);
    int* dg = deg + (size_t)r * N;
    int* rs = rowstart + (size_t)r * (N + 1);
    float* dv = dinv + (size_t)r * N;
    __shared__ int wsum[4];
    int v[4]; int tsum = 0;
    #pragma unroll
    for (int j = 0; j < 4; ++j) {
        int idx = start + tid * 4 + j;
        v[j] = (idx < end) ? dg[idx] : 0;
        tsum += v[j];
    }
    int sc = tsum;
    #pragma unroll
    for (int off = 1; off < 64; off <<= 1) {
        int t = __shfl_up(sc, off, 64);
        if (lane >= off) sc += t;
    }
    if (lane == 63) wsum[wv] = sc;
    __syncthreads();
    int woff = 0;
    for (int w = 0; w < wv; ++w) woff += wsum[w];
    int excl = psum[r * NCHUNK + b] + woff + sc - tsum;
    #pragma unroll
    for (int j = 0; j < 4; ++j) {
        int idx = start + tid * 4 + j;
        if (idx < end) {
            rs[idx] = excl;
            dg[idx] = excl;                       // cursor for fill_csr
            dv[idx] = rsqrtf((float)(v[j] + 1));  // +1 self-loop
        }
        excl += v[j];
    }
}

// ---------------- fill CSR: bucket edges by dst; store (src, perm[src]) -----
__global__ __launch_bounds__(256) void fill_csr(const int* __restrict__ ei,
                                                const int* __restrict__ perm,
                                                int* __restrict__ cursor,
                                                int2* __restrict__ csr,
                                                int N, int E) {
    int r = blockIdx.y;
    int e = blockIdx.x * 256 + threadIdx.x;
    if (e >= E) return;
    const int* base = ei + (size_t)r * 2 * E;
    int s = base[e], d = base[E + e];
    int pos = atomicAdd(&cursor[(size_t)r * N + d], 1);
    int2 sp; sp.x = s; sp.y = perm[(size_t)r * N + s];
    csr[(size_t)r * E + pos] = sp;
}

// ---------------- XW = x @ W_r: 64x64 tile/block, 4x4 microtile/thread ------
// LDS: W full (128x64, pad 68) + x k-chunk (64x64 transposed, pad 68) = 52 KB
// -> 3 blocks/CU. Inner loop: 2 ds_read_b128 + 16 FMA per k.
__global__ __launch_bounds__(256) void gemm_xw(const float* __restrict__ x,
                                               const float* __restrict__ W,
                                               float* __restrict__ xw,
                                               int N) {
    __shared__ float xs[64 * 68];    // [kk][row], stride 68
    __shared__ float wsd[128 * 68];  // [k][col],  stride 68
    int r = blockIdx.y;
    const float* Wr = W + (size_t)r * F_IN * F_OUT;
    {   // stage W once: thread t -> k = t>>1, cq = t&1, 8 float4 each
        int k = threadIdx.x >> 1, cq = threadIdx.x & 1;
        const float* wrow = Wr + k * F_OUT;
        #pragma unroll
        for (int j = 0; j < 8; ++j) {
            int col = (cq + 2 * j) * 4;
            *(float4*)&wsd[k * 68 + col] = *(const float4*)(wrow + col);
        }
    }
    int row0 = blockIdx.x * 64;
    int ty = threadIdx.x >> 4, tx = threadIdx.x & 15;
    int lrow = threadIdx.x >> 2;       // 0..63: staging row
    int kq = threadIdx.x & 3;          // 4 threads per row
    int grow = row0 + lrow; if (grow >= N) grow = N - 1;   // clamp, garbage ok
    const float* xrow = x + (size_t)grow * F_IN;
    float acc[4][4] = {};
    for (int kc = 0; kc < 2; ++kc) {
        __syncthreads();   // xs reuse (and W visibility before first compute)
        #pragma unroll
        for (int j = 0; j < 4; ++j) {
            int kk4 = kq + 4 * j;                       // float4 idx within 16
            float4 v = *(const float4*)(xrow + kc * 64 + kk4 * 4);
            xs[(kk4 * 4 + 0) * 68 + lrow] = v.x;
            xs[(kk4 * 4 + 1) * 68 + lrow] = v.y;
            xs[(kk4 * 4 + 2) * 68 + lrow] = v.z;
            xs[(kk4 * 4 + 3) * 68 + lrow] = v.w;
        }
        __syncthreads();
        const float* wk = &wsd[kc * 64 * 68];
        #pragma unroll 8
        for (int kk = 0; kk < 64; ++kk) {
            float4 xa = *(const float4*)&xs[kk * 68 + ty * 4];
            float4 wb = *(const float4*)&wk[kk * 68 + tx * 4];
            acc[0][0] += xa.x * wb.x; acc[0][1] += xa.x * wb.y;
            acc[0][2] += xa.x * wb.z; acc[0][3] += xa.x * wb.w;
            acc[1][0] += xa.y * wb.x; acc[1][1] += xa.y * wb.y;
            acc[1][2] += xa.y * wb.z; acc[1][3] += xa.y * wb.w;
            acc[2][0] += xa.z * wb.x; acc[2][1] += xa.z * wb.y;
            acc[2][2] += xa.z * wb.z; acc[2][3] += xa.z * wb.w;
            acc[3][0] += xa.w * wb.x; acc[3][1] += xa.w * wb.y;
            acc[3][2] += xa.w * wb.z; acc[3][3] += xa.w * wb.w;
        }
    }
    #pragma unroll
    for (int i = 0; i < 4; ++i) {
        int orow = row0 + ty * 4 + i;
        if (orow < N) {
            float4 v = make_float4(acc[i][0], acc[i][1], acc[i][2], acc[i][3]);
            *(float4*)(xw + ((size_t)r * N + orow) * F_OUT + tx * 4) = v;
        }
    }
}

// ---------------- gather: one wave per (r, dst row); fused epilogue ---------
__global__ __launch_bounds__(256) void gather_kernel(const int2* __restrict__ csr,
                                                     const int* __restrict__ rowstart,
                                                     const float* __restrict__ dinv,
                                                     const int* __restrict__ perm,
                                                     const float* __restrict__ xw,
                                                     const float* __restrict__ bs,
                                                     float* __restrict__ out_pos,
                                                     float* __restrict__ out_neg,
                                                     float* __restrict__ partial,
                                                     int N, int E) {
    int r = blockIdx.y;
    int lane = threadIdx.x & 63, wv = threadIdx.x >> 6;
    int i = blockIdx.x * 4 + wv;
    __shared__ float ls[256];
    float psum = 0.f;
    if (i < N) {
        const float* dv  = dinv + (size_t)r * N;
        const float* xwr = xw + (size_t)r * N * F_OUT;
        float di = dv[i];
        float w = di * di;
        float accp = xwr[(size_t)i * F_OUT + lane] * w;
        int pi = perm[(size_t)r * N + i];
        float accn = xwr[(size_t)pi * F_OUT + lane] * w;
        const int* rs = rowstart + (size_t)r * (N + 1);
        int j0 = rs[i], j1 = rs[i + 1];
        const int2* cs = csr + (size_t)r * E;
        int j = j0;
        for (; j + 1 < j1; j += 2) {     // 2-deep unroll for MLP
            int2 a = cs[j], b2 = cs[j + 1];
            float na = dv[a.x] * di, nb = dv[b2.x] * di;
            accp += xwr[(size_t)a.x  * F_OUT + lane] * na;
            accn += xwr[(size_t)a.y  * F_OUT + lane] * na;
            accp += xwr[(size_t)b2.x * F_OUT + lane] * nb;
            accn += xwr[(size_t)b2.y * F_OUT + lane] * nb;
        }
        if (j < j1) {
            int2 a = cs[j];
            float na = dv[a.x] * di;
            accp += xwr[(size_t)a.x * F_OUT + lane] * na;
            accn += xwr[(size_t)a.y * F_OUT + lane] * na;
        }
        float b = bs[r * F_OUT + lane];
        float p = accp + b; p = p > 0.f ? p : 0.f;
        float q = accn + b; q = q > 0.f ? q : 0.f;
        size_t off = (size_t)r * N * F_OUT + (size_t)i * F_OUT + lane;
        out_pos[off] = p;
        out_neg[off] = q;
        psum = p;
    }
    ls[threadIdx.x] = psum;
    __syncthreads();
    if (wv == 0) {
        float t = ls[lane] + ls[64 + lane] + ls[128 + lane] + ls[192 + lane];
        atomicAdd(&partial[((size_t)r * 256 + (blockIdx.x & 255)) * F_OUT + lane], t);
    }
}

// ---------------- summary = mean over pos rows ------------------------------
__global__ __launch_bounds__(256) void summary_reduce(const float* __restrict__ partial,
                                                      float* __restrict__ summary,
                                                      float inv_n) {
    int r = blockIdx.x;
    int lane = threadIdx.x & 63, wv = threadIdx.x >> 6;
    __shared__ float ls[256];
    float s = 0.f;
    for (int c = wv; c < 256; c += 4)
        s += partial[((size_t)r * 256 + c) * F_OUT + lane];
    ls[threadIdx.x] = s;
    __syncthreads();
    if (wv == 0)
        summary[r * F_OUT + lane] =
            (ls[lane] + ls[64 + lane] + ls[128 + lane] + ls[192 + lane]) * inv_n;
}

extern "C" void kernel_launch(void* const* d_in, const int* in_sizes, int n_in,
                              void* d_out, int out_size, void* d_ws, size_t ws_size,
                              hipStream_t stream) {
    const float* x    = (const float*)d_in[0];
    const int*   ei   = (const int*)d_in[1];
    const int*   perm = (const int*)d_in[2];
    const float* Ws   = (const float*)d_in[3];
    const float* bs   = (const float*)d_in[4];

    const int N = in_sizes[0] / F_IN;          // 100000
    const int R = in_sizes[4] / F_OUT;         // 3
    const int E = in_sizes[1] / (2 * R);       // 600000

    float* out_pos = (float*)d_out;
    float* out_neg = out_pos + (size_t)R * N * F_OUT;
    float* summary = out_neg + (size_t)R * N * F_OUT;

    char* ws = (char*)d_ws;
    size_t off = 0;
    auto alloc = [&](size_t bytes) { void* p = ws + off;
        off += (bytes + 15) & ~(size_t)15; return p; };
    int*   deg      = (int*)  alloc((size_t)R * N * 4);   // -> cursor after scan
    float* dinv     = (float*)alloc((size_t)R * N * 4);
    int*   rowstart = (int*)  alloc((size_t)R * (N + 1) * 4);
    int2*  csr      = (int2*) alloc((size_t)R * E * 8);
    float* xw       = (float*)alloc((size_t)R * N * F_OUT * 4);
    float* partial  = (float*)alloc((size_t)R * 256 * F_OUT * 4);
    int*   psum     = (int*)  alloc((size_t)R * NCHUNK * 4);

    const int chunk = (N + NCHUNK - 1) / NCHUNK;   // 391 for N=100000 (<=1024)

    hipMemsetAsync(deg, 0, (size_t)R * N * sizeof(int), stream);
    hipMemsetAsync(partial, 0, (size_t)R * 256 * F_OUT * sizeof(float), stream);

    deg_kernel<<<dim3((E + 255) / 256, R), 256, 0, stream>>>(ei, deg, N, E);
    scan_partial<<<dim3(NCHUNK, R), 256, 0, stream>>>(deg, psum, N, chunk);
    scan_offsets<<<1, 256, 0, stream>>>(psum, rowstart, N, R);
    scan_apply<<<dim3(NCHUNK, R), 256, 0, stream>>>(deg, psum, rowstart, dinv, N, chunk);
    fill_csr<<<dim3((E + 255) / 256, R), 256, 0, stream>>>(ei, perm, deg, csr, N, E);
    gemm_xw<<<dim3((N + 63) / 64, R), 256, 0, stream>>>(x, Ws, xw, N);
    gather_kernel<<<dim3((N + 3) / 4, R), 256, 0, stream>>>(csr, rowstart, dinv, perm,
                                                            xw, bs, out_pos, out_neg,
                                                            partial, N, E);
    summary_reduce<<<R, 256, 0, stream>>>(partial, summary, 1.0f / (float)N);
}

// Round 4
// 615.734 us; speedup vs baseline: 2.3173x; 1.0715x over previous
//
#include <hip/hip_runtime.h>

#define F_IN 128
#define F_OUT 64
#define NCHUNK 256   // scan chunks per relation

__device__ __forceinline__ unsigned short f2bf(float f) {
    unsigned int u = __float_as_uint(f);
    u += 0x7fff + ((u >> 16) & 1);          // round-nearest-even
    return (unsigned short)(u >> 16);
}
__device__ __forceinline__ float bf2f(unsigned short s) {
    return __uint_as_float((unsigned int)s << 16);
}

// ---------------- degree (dst occurrences; +1 self-loop added later) --------
__global__ __launch_bounds__(256) void deg_kernel(const int* __restrict__ ei,
                                                  int* __restrict__ deg,
                                                  int N, int E) {
    int r = blockIdx.y;
    int e = blockIdx.x * 256 + threadIdx.x;
    if (e >= E) return;
    int d = ei[(size_t)r * 2 * E + E + e];
    atomicAdd(&deg[(size_t)r * N + d], 1);
}

// ---------------- invperm: ip[perm[i]] = i ----------------------------------
__global__ __launch_bounds__(256) void invperm_kernel(const int* __restrict__ perm,
                                                      int* __restrict__ ip, int N) {
    int r = blockIdx.y;
    int i = blockIdx.x * 256 + threadIdx.x;
    if (i >= N) return;
    ip[(size_t)r * N + perm[(size_t)r * N + i]] = i;
}

// ---------------- hierarchical scan, phase 1: per-chunk sums ----------------
__global__ __launch_bounds__(256) void scan_partial(const int* __restrict__ deg,
                                                    int* __restrict__ psum,
                                                    int N, int chunk) {
    int r = blockIdx.y, b = blockIdx.x;
    int start = b * chunk, end = min(start + chunk, N);
    int s = 0;
    for (int i = start + threadIdx.x; i < end; i += 256)
        s += deg[(size_t)r * N + i];
    __shared__ int ls[256];
    ls[threadIdx.x] = s;
    __syncthreads();
    for (int off = 128; off > 0; off >>= 1) {
        if (threadIdx.x < off) ls[threadIdx.x] += ls[threadIdx.x + off];
        __syncthreads();
    }
    if (threadIdx.x == 0) psum[r * NCHUNK + b] = ls[0];
}

// ---------------- phase 2: exclusive scan of chunk sums (1 block) -----------
__global__ __launch_bounds__(256) void scan_offsets(int* __restrict__ psum,
                                                    int* __restrict__ rowstart,
                                                    int N, int R) {
    int tid = threadIdx.x, lane = tid & 63, wv = tid >> 6;
    __shared__ int wsum[4];
    for (int r = 0; r < R; ++r) {
        int v = psum[r * NCHUNK + tid];
        int sc = v;
        #pragma unroll
        for (int off = 1; off < 64; off <<= 1) {
            int t = __shfl_up(sc, off, 64);
            if (lane >= off) sc += t;
        }
        if (lane == 63) wsum[wv] = sc;
        __syncthreads();
        int woff = 0;
        for (int w = 0; w < wv; ++w) woff += wsum[w];
        psum[r * NCHUNK + tid] = woff + sc - v;   // exclusive
        if (tid == 255) rowstart[(size_t)r * (N + 1) + N] = woff + sc;  // total
        __syncthreads();
    }
}

// ---------------- phase 3: re-scan chunk, write rowstart/cursor/dinv --------
__global__ __launch_bounds__(256) void scan_apply(int* __restrict__ deg,
                                                  const int* __restrict__ psum,
                                                  int* __restrict__ rowstart,
                                                  float* __restrict__ dinv,
                                                  int N, int chunk) {
    int r = blockIdx.y, b = blockIdx.x;
    int tid = threadIdx.x, lane = tid & 63, wv = tid >> 6;
    int start = b * chunk, end = min(start + chunk, N);
    int* dg = deg + (size_t)r * N;
    int* rs = rowstart + (size_t)r * (N + 1);
    float* dv = dinv + (size_t)r * N;
    __shared__ int wsum[4];
    int v[4]; int tsum = 0;
    #pragma unroll
    for (int j = 0; j < 4; ++j) {
        int idx = start + tid * 4 + j;
        v[j] = (idx < end) ? dg[idx] : 0;
        tsum += v[j];
    }
    int sc = tsum;
    #pragma unroll
    for (int off = 1; off < 64; off <<= 1) {
        int t = __shfl_up(sc, off, 64);
        if (lane >= off) sc += t;
    }
    if (lane == 63) wsum[wv] = sc;
    __syncthreads();
    int woff = 0;
    for (int w = 0; w < wv; ++w) woff += wsum[w];
    int excl = psum[r * NCHUNK + b] + woff + sc - tsum;
    #pragma unroll
    for (int j = 0; j < 4; ++j) {
        int idx = start + tid * 4 + j;
        if (idx < end) {
            rs[idx] = excl;
            dg[idx] = excl;                       // cursor for fill_csr
            dv[idx] = rsqrtf((float)(v[j] + 1));  // +1 self-loop
        }
        excl += v[j];
    }
}

// ---------------- fill CSR: bucket by dst; store (src, norm) ----------------
__global__ __launch_bounds__(256) void fill_csr(const int* __restrict__ ei,
                                                const float* __restrict__ dinv,
                                                int* __restrict__ cursor,
                                                int2* __restrict__ csr,
                                                int N, int E) {
    int r = blockIdx.y;
    int e = blockIdx.x * 256 + threadIdx.x;
    if (e >= E) return;
    const int* base = ei + (size_t)r * 2 * E;
    int s = base[e], d = base[E + e];
    const float* dv = dinv + (size_t)r * N;
    float nrm = dv[s] * dv[d];
    int pos = atomicAdd(&cursor[(size_t)r * N + d], 1);
    int2 sp; sp.x = s; sp.y = __float_as_int(nrm);
    csr[(size_t)r * E + pos] = sp;
}

// ---------------- XW = x @ W_r -> bf16 combined[i] = (xw[i] | xw[perm[i]]) --
// 64x64 tile/block, 4x4 microtile/thread. Row i's result written to
// combined[i][0:64] (pos) and combined[invperm[i]][64:128] (neg half).
__global__ __launch_bounds__(256) void gemm_xw(const float* __restrict__ x,
                                               const float* __restrict__ W,
                                               const int* __restrict__ ip,
                                               unsigned short* __restrict__ combined,
                                               int N) {
    __shared__ float xs[64 * 68];    // [kk][row], stride 68
    __shared__ float wsd[128 * 68];  // [k][col],  stride 68
    int r = blockIdx.y;
    const float* Wr = W + (size_t)r * F_IN * F_OUT;
    {   // stage W once: thread t -> k = t>>1, cq = t&1, 8 float4 each
        int k = threadIdx.x >> 1, cq = threadIdx.x & 1;
        const float* wrow = Wr + k * F_OUT;
        #pragma unroll
        for (int j = 0; j < 8; ++j) {
            int col = (cq + 2 * j) * 4;
            *(float4*)&wsd[k * 68 + col] = *(const float4*)(wrow + col);
        }
    }
    int row0 = blockIdx.x * 64;
    int ty = threadIdx.x >> 4, tx = threadIdx.x & 15;
    int lrow = threadIdx.x >> 2;
    int kq = threadIdx.x & 3;
    int grow = row0 + lrow; if (grow >= N) grow = N - 1;   // clamp, garbage ok
    const float* xrow = x + (size_t)grow * F_IN;
    float acc[4][4] = {};
    for (int kc = 0; kc < 2; ++kc) {
        __syncthreads();
        #pragma unroll
        for (int j = 0; j < 4; ++j) {
            int kk4 = kq + 4 * j;
            float4 v = *(const float4*)(xrow + kc * 64 + kk4 * 4);
            xs[(kk4 * 4 + 0) * 68 + lrow] = v.x;
            xs[(kk4 * 4 + 1) * 68 + lrow] = v.y;
            xs[(kk4 * 4 + 2) * 68 + lrow] = v.z;
            xs[(kk4 * 4 + 3) * 68 + lrow] = v.w;
        }
        __syncthreads();
        const float* wk = &wsd[kc * 64 * 68];
        #pragma unroll 8
        for (int kk = 0; kk < 64; ++kk) {
            float4 xa = *(const float4*)&xs[kk * 68 + ty * 4];
            float4 wb = *(const float4*)&wk[kk * 68 + tx * 4];
            acc[0][0] += xa.x * wb.x; acc[0][1] += xa.x * wb.y;
            acc[0][2] += xa.x * wb.z; acc[0][3] += xa.x * wb.w;
            acc[1][0] += xa.y * wb.x; acc[1][1] += xa.y * wb.y;
            acc[1][2] += xa.y * wb.z; acc[1][3] += xa.y * wb.w;
            acc[2][0] += xa.z * wb.x; acc[2][1] += xa.z * wb.y;
            acc[2][2] += xa.z * wb.z; acc[2][3] += xa.z * wb.w;
            acc[3][0] += xa.w * wb.x; acc[3][1] += xa.w * wb.y;
            acc[3][2] += xa.w * wb.z; acc[3][3] += xa.w * wb.w;
        }
    }
    const int* ipr = ip + (size_t)r * N;
    #pragma unroll
    for (int i = 0; i < 4; ++i) {
        int orow = row0 + ty * 4 + i;
        if (orow < N) {
            ushort4 v;
            v.x = f2bf(acc[i][0]); v.y = f2bf(acc[i][1]);
            v.z = f2bf(acc[i][2]); v.w = f2bf(acc[i][3]);
            size_t rb = (size_t)r * N;
            // pos half: own row (coalesced)
            *(ushort4*)(combined + (rb + orow) * 128 + tx * 4) = v;
            // neg half of row ip[orow]: wave writes 4 x 128B full segments
            int j = ipr[orow];
            *(ushort4*)(combined + (rb + j) * 128 + 64 + tx * 4) = v;
        }
    }
}

// ---------------- gather: one wave per (r, dst row); fused epilogue ---------
__global__ __launch_bounds__(256) void gather_kernel(const int2* __restrict__ csr,
                                                     const int* __restrict__ rowstart,
                                                     const float* __restrict__ dinv,
                                                     const unsigned short* __restrict__ combined,
                                                     const float* __restrict__ bs,
                                                     float* __restrict__ out_pos,
                                                     float* __restrict__ out_neg,
                                                     float* __restrict__ partial,
                                                     int N, int E) {
    int r = blockIdx.y;
    int lane = threadIdx.x & 63, wv = threadIdx.x >> 6;
    int i = blockIdx.x * 4 + wv;
    __shared__ float ls[256];
    float psum = 0.f;
    if (i < N) {
        const unsigned short* cw = combined + (size_t)r * N * 128;
        float di = dinv[(size_t)r * N + i];
        float w = di * di;
        const unsigned short* ci = cw + (size_t)i * 128;
        float accp = bf2f(ci[lane]) * w;
        float accn = bf2f(ci[64 + lane]) * w;
        const int* rs = rowstart + (size_t)r * (N + 1);
        int j0 = rs[i], j1 = rs[i + 1];
        const int2* cs = csr + (size_t)r * E;
        int j = j0;
        for (; j + 1 < j1; j += 2) {     // 2-deep unroll for MLP
            int2 a = cs[j], b2 = cs[j + 1];
            const unsigned short* ca = cw + (size_t)a.x * 128;
            const unsigned short* cb = cw + (size_t)b2.x * 128;
            unsigned short pa = ca[lane], qa = ca[64 + lane];
            unsigned short pb = cb[lane], qb = cb[64 + lane];
            float na = __int_as_float(a.y), nb = __int_as_float(b2.y);
            accp += bf2f(pa) * na; accn += bf2f(qa) * na;
            accp += bf2f(pb) * nb; accn += bf2f(qb) * nb;
        }
        if (j < j1) {
            int2 a = cs[j];
            const unsigned short* ca = cw + (size_t)a.x * 128;
            float na = __int_as_float(a.y);
            accp += bf2f(ca[lane]) * na;
            accn += bf2f(ca[64 + lane]) * na;
        }
        float b = bs[r * F_OUT + lane];
        float p = accp + b; p = p > 0.f ? p : 0.f;
        float q = accn + b; q = q > 0.f ? q : 0.f;
        size_t off = (size_t)r * N * F_OUT + (size_t)i * F_OUT + lane;
        out_pos[off] = p;
        out_neg[off] = q;
        psum = p;
    }
    ls[threadIdx.x] = psum;
    __syncthreads();
    if (wv == 0) {
        float t = ls[lane] + ls[64 + lane] + ls[128 + lane] + ls[192 + lane];
        atomicAdd(&partial[((size_t)r * 256 + (blockIdx.x & 255)) * F_OUT + lane], t);
    }
}

// ---------------- summary = mean over pos rows ------------------------------
__global__ __launch_bounds__(256) void summary_reduce(const float* __restrict__ partial,
                                                      float* __restrict__ summary,
                                                      float inv_n) {
    int r = blockIdx.x;
    int lane = threadIdx.x & 63, wv = threadIdx.x >> 6;
    __shared__ float ls[256];
    float s = 0.f;
    for (int c = wv; c < 256; c += 4)
        s += partial[((size_t)r * 256 + c) * F_OUT + lane];
    ls[threadIdx.x] = s;
    __syncthreads();
    if (wv == 0)
        summary[r * F_OUT + lane] =
            (ls[lane] + ls[64 + lane] + ls[128 + lane] + ls[192 + lane]) * inv_n;
}

extern "C" void kernel_launch(void* const* d_in, const int* in_sizes, int n_in,
                              void* d_out, int out_size, void* d_ws, size_t ws_size,
                              hipStream_t stream) {
    const float* x    = (const float*)d_in[0];
    const int*   ei   = (const int*)d_in[1];
    const int*   perm = (const int*)d_in[2];
    const float* Ws   = (const float*)d_in[3];
    const float* bs   = (const float*)d_in[4];

    const int N = in_sizes[0] / F_IN;          // 100000
    const int R = in_sizes[4] / F_OUT;         // 3
    const int E = in_sizes[1] / (2 * R);       // 600000

    float* out_pos = (float*)d_out;
    float* out_neg = out_pos + (size_t)R * N * F_OUT;
    float* summary = out_neg + (size_t)R * N * F_OUT;

    char* ws = (char*)d_ws;
    size_t off = 0;
    auto alloc = [&](size_t bytes) { void* p = ws + off;
        off += (bytes + 255) & ~(size_t)255; return p; };
    int*   deg      = (int*)  alloc((size_t)R * N * 4);   // -> cursor after scan
    float* dinv     = (float*)alloc((size_t)R * N * 4);
    int*   rowstart = (int*)  alloc((size_t)R * (N + 1) * 4);
    int*   ip       = (int*)  alloc((size_t)R * N * 4);
    int2*  csr      = (int2*) alloc((size_t)R * E * 8);
    unsigned short* combined = (unsigned short*)alloc((size_t)R * N * 128 * 2);
    float* partial  = (float*)alloc((size_t)R * 256 * F_OUT * 4);
    int*   psum     = (int*)  alloc((size_t)R * NCHUNK * 4);

    const int chunk = (N + NCHUNK - 1) / NCHUNK;

    hipMemsetAsync(deg, 0, (size_t)R * N * sizeof(int), stream);
    hipMemsetAsync(partial, 0, (size_t)R * 256 * F_OUT * sizeof(float), stream);

    deg_kernel<<<dim3((E + 255) / 256, R), 256, 0, stream>>>(ei, deg, N, E);
    invperm_kernel<<<dim3((N + 255) / 256, R), 256, 0, stream>>>(perm, ip, N);
    scan_partial<<<dim3(NCHUNK, R), 256, 0, stream>>>(deg, psum, N, chunk);
    scan_offsets<<<1, 256, 0, stream>>>(psum, rowstart, N, R);
    scan_apply<<<dim3(NCHUNK, R), 256, 0, stream>>>(deg, psum, rowstart, dinv, N, chunk);
    fill_csr<<<dim3((E + 255) / 256, R), 256, 0, stream>>>(ei, dinv, deg, csr, N, E);
    gemm_xw<<<dim3((N + 63) / 64, R), 256, 0, stream>>>(x, Ws, ip, combined, N);
    gather_kernel<<<dim3((N + 3) / 4, R), 256, 0, stream>>>(csr, rowstart, dinv,
                                                            combined, bs, out_pos,
                                                            out_neg, partial, N, E);
    summary_reduce<<<R, 256, 0, stream>>>(partial, summary, 1.0f / (float)N);
}